// Round 1
// baseline (65.167 us; speedup 1.0000x reference)
//
#include <hip/hip_runtime.h>

// One thread per patch. B*196 patches total.
// Patch (b, p): r = p/14, c = p%14; pixels at x[b*784 + 2r*28 + 2c + {0,1}] and +28.
// state[d], d = i*8+j*4+k*2+l over wires (i,j,k,l); q(wire)=[cos(h),sin(h)].
// y = U @ state (row-major U[e*16+d]); meas[w] = sum_e sign(bit(3-w) of e) * y_e^2.

__global__ __launch_bounds__(256) void quanv_kernel(
    const float* __restrict__ x,
    const float* __restrict__ U,
    float* __restrict__ out,
    int total)
{
    int g = blockIdx.x * 256 + threadIdx.x;
    if (g >= total) return;

    int b = g / 196;
    int p = g - b * 196;
    int r = p / 14;
    int c = p - r * 14;

    const float* base = x + b * 784 + r * 56 + c * 2;
    float2 top = *reinterpret_cast<const float2*>(base);
    float2 bot = *reinterpret_cast<const float2*>(base + 28);

    float h0 = 0.5f * top.x, h1 = 0.5f * top.y;
    float h2 = 0.5f * bot.x, h3 = 0.5f * bot.y;

    float s0, c0, s1, c1, s2, c2, s3, c3;
    __sincosf(h0, &s0, &c0);
    __sincosf(h1, &s1, &c1);
    __sincosf(h2, &s2, &c2);
    __sincosf(h3, &s3, &c3);

    // kron over (wire0,wire1) -> a[ij], (wire2,wire3) -> q[kl]; st[ij*4+kl]=a*q
    float a0 = c0 * c1, a1 = c0 * s1, a2 = s0 * c1, a3 = s0 * s1;
    float q0 = c2 * c3, q1 = c2 * s3, q2 = s2 * c3, q3 = s2 * s3;

    float st[16];
    st[ 0] = a0 * q0; st[ 1] = a0 * q1; st[ 2] = a0 * q2; st[ 3] = a0 * q3;
    st[ 4] = a1 * q0; st[ 5] = a1 * q1; st[ 6] = a1 * q2; st[ 7] = a1 * q3;
    st[ 8] = a2 * q0; st[ 9] = a2 * q1; st[10] = a2 * q2; st[11] = a2 * q3;
    st[12] = a3 * q0; st[13] = a3 * q1; st[14] = a3 * q2; st[15] = a3 * q3;

    // Fused matvec + square + PauliZ reduction.
    // U is read with wave-uniform indices -> scalar (s_load) broadcast path.
    float m0 = 0.f, m1 = 0.f, m2 = 0.f, m3 = 0.f;
    #pragma unroll
    for (int e = 0; e < 16; ++e) {
        float y = 0.f;
        #pragma unroll
        for (int d = 0; d < 16; ++d)
            y = fmaf(U[e * 16 + d], st[d], y);
        float y2 = y * y;
        m0 += (e & 8) ? -y2 : y2;
        m1 += (e & 4) ? -y2 : y2;
        m2 += (e & 2) ? -y2 : y2;
        m3 += (e & 1) ? -y2 : y2;
    }

    float4 res = make_float4(m0, m1, m2, m3);
    *reinterpret_cast<float4*>(out + (size_t)g * 4) = res;
}

extern "C" void kernel_launch(void* const* d_in, const int* in_sizes, int n_in,
                              void* d_out, int out_size, void* d_ws, size_t ws_size,
                              hipStream_t stream) {
    const float* x = (const float*)d_in[0];
    const float* U = (const float*)d_in[1];
    float* out = (float*)d_out;

    int B = in_sizes[0] / 784;
    int total = B * 196;                 // 6,422,528 for B=32768
    int blocks = (total + 255) / 256;    // 25,088

    quanv_kernel<<<blocks, 256, 0, stream>>>(x, U, out, total);
}

// Round 2
// 55.554 us; speedup vs baseline: 1.1730x; 1.1730x over previous
//
#include <hip/hip_runtime.h>

typedef _Float16 half4 __attribute__((ext_vector_type(4)));
typedef float f32x4 __attribute__((ext_vector_type(4)));

// Per 16 patches (one wave iteration):
//   MFMA1: Y = U(16x16) * ST^T(16x16)   A=U, B[d][p]=st[p][d]
//   MFMA2: M = Ztile(16x16) * (Y.^2)    A=Z-sign tile, B = squared D1 (layouts match!)
// Lane l: g=l>>4 (k-block), p16=l&15 (patch/col).
//   B1 frag: st[p16][4g+i] = a[g] * q[i]   (kron structure aligns with k-blocking)
//   D1 frag: Y[4g+i][p16] -> square -> B2 frag (bit-identical layout)
//   D2 frag: M[4g+i][p16] = meas[w=i][p16]  (Ztile row m has wire w=m&3)
__global__ __launch_bounds__(256) void quanv_mfma(
    const float* __restrict__ x,
    const float* __restrict__ U,
    float* __restrict__ out,
    int total, int ipw, int rem)
{
    const int lane = threadIdx.x & 63;
    const int wave = (blockIdx.x * blockDim.x + threadIdx.x) >> 6;
    const int p16  = lane & 15;
    const int g    = lane >> 4;

    const f32x4 zero4 = {0.f, 0.f, 0.f, 0.f};

    // Resident A1 = U fragment: U[p16][4g+i]
    half4 aU;
    {
        const float* up = U + p16 * 16 + 4 * g;
        aU[0] = (_Float16)up[0];
        aU[1] = (_Float16)up[1];
        aU[2] = (_Float16)up[2];
        aU[3] = (_Float16)up[3];
    }
    // Resident A2 = tiled PauliZ sign matrix: Ztile[m][e] = z_{m&3}(e), exact in f16
    half4 aS;
    {
        int w = p16 & 3;
        #pragma unroll
        for (int i = 0; i < 4; ++i) {
            int e = 4 * g + i;
            aS[i] = ((e >> (3 - w)) & 1) ? (_Float16)-1.f : (_Float16)1.f;
        }
    }

    const int cnt = ipw + (wave < rem ? 1 : 0);
    const int it0 = wave * ipw + (wave < rem ? wave : rem);

    for (int j = 0; j < cnt; ++j) {
        const int patch = (it0 + j) * 16 + p16;
        const int pc = patch < total ? patch : total - 1;
        // patch -> (image, row, col); lane loads pixel g of its patch
        int b  = pc / 196;
        int pp = pc - b * 196;
        int r  = pp / 14;
        int c  = pp - r * 14;
        int addr = b * 784 + r * 56 + 2 * c + (g & 1) + 28 * (g >> 1);
        float h = 0.5f * x[addr];
        float sn, cs;
        __sincosf(h, &sn, &cs);

        // broadcast cos/sin of pixels 0..3 (held by lane groups 0..3) for this patch
        float c0 = __shfl(cs, p16);
        float s0 = __shfl(sn, p16);
        float c1 = __shfl(cs, p16 + 16);
        float s1 = __shfl(sn, p16 + 16);
        float c2 = __shfl(cs, p16 + 32);
        float s2 = __shfl(sn, p16 + 32);
        float c3 = __shfl(cs, p16 + 48);
        float s3 = __shfl(sn, p16 + 48);

        // st[d=4g+i] = a[g]*q[i];  a[g] selects (c0|s0)(c1|s1), q = (c2,s2)x(c3,s3)
        float fa = ((g & 2) ? s0 : c0) * ((g & 1) ? s1 : c1);
        half4 bST;
        bST[0] = (_Float16)(fa * (c2 * c3));
        bST[1] = (_Float16)(fa * (c2 * s3));
        bST[2] = (_Float16)(fa * (s2 * c3));
        bST[3] = (_Float16)(fa * (s2 * s3));

        f32x4 y = __builtin_amdgcn_mfma_f32_16x16x16f16(aU, bST, zero4, 0, 0, 0);

        half4 bP;
        bP[0] = (_Float16)(y[0] * y[0]);
        bP[1] = (_Float16)(y[1] * y[1]);
        bP[2] = (_Float16)(y[2] * y[2]);
        bP[3] = (_Float16)(y[3] * y[3]);

        f32x4 m = __builtin_amdgcn_mfma_f32_16x16x16f16(aS, bP, zero4, 0, 0, 0);

        if (g == 0 && patch < total) {
            float4 res = make_float4(m[0], m[1], m[2], m[3]);
            *reinterpret_cast<float4*>(out + (size_t)patch * 4) = res;
        }
    }
}

extern "C" void kernel_launch(void* const* d_in, const int* in_sizes, int n_in,
                              void* d_out, int out_size, void* d_ws, size_t ws_size,
                              hipStream_t stream) {
    const float* x = (const float*)d_in[0];
    const float* U = (const float*)d_in[1];
    float* out = (float*)d_out;

    int B = in_sizes[0] / 784;
    int total = B * 196;                 // 6,422,528 patches
    int nit = (total + 15) / 16;         // 16-patch MFMA batches

    int nblocks = 2048;                  // 8192 waves -> 49 batches/wave at B=32768
    int nwaves = nblocks * (256 / 64);
    int ipw = nit / nwaves;
    int rem = nit % nwaves;

    quanv_mfma<<<nblocks, 256, 0, stream>>>(x, U, out, total, ipw, rem);
}

// Round 4
// 52.836 us; speedup vs baseline: 1.2334x; 1.0514x over previous
//
#include <hip/hip_runtime.h>

typedef _Float16 half4 __attribute__((ext_vector_type(4)));
typedef __fp16 fp16x2 __attribute__((ext_vector_type(2)));
typedef float f32x4 __attribute__((ext_vector_type(4)));

// rev = pixel * 0.5 rad / (2*pi)
#define SINCONST 0.07957747154594767f

// pp in [0,227] -> row = pp/14 via magic mul (verified exact for pp<=195+32)
__device__ __forceinline__ int elem_of(int pp, int bofs) {
    int r = (pp * 2341) >> 15;
    return bofs + 2 * pp + 28 * r;   // b*784 + 2c + 56r, always even
}

__device__ __forceinline__ void ldpix(const float* __restrict__ x, int e,
                                      float2& top, float2& bot) {
    const float2* p = reinterpret_cast<const float2*>(x + e);
    top = p[0];     // pixels (r,c),(r,c+1)
    bot = p[14];    // pixels (r+1,c),(r+1,c+1)  (+28 floats)
}

// One 16-patch batch: MFMA1 Y=U*ST^T, square, MFMA2 M=Ztile*Y.^2, store (g==0).
__device__ __forceinline__ void compute_batch(
    float2 top, float2 bot, float q0, float q1,
    half4 aU, half4 aS, int patch, int g,
    float* __restrict__ out, int total)
{
    // sel(cos/sin) via +0.25 rev: sin(2pi(x+0.25)) = cos(2pi x)
    float t0 = __builtin_amdgcn_sinf(fmaf(top.x, SINCONST, q0));
    float t1 = __builtin_amdgcn_sinf(fmaf(top.y, SINCONST, q1));
    float fa = t0 * t1;
    float r2 = bot.x * SINCONST;
    float r3 = bot.y * SINCONST;
    float s2 = __builtin_amdgcn_sinf(r2);
    float c2 = __builtin_amdgcn_sinf(r2 + 0.25f);
    float s3 = __builtin_amdgcn_sinf(r3);
    float c3 = __builtin_amdgcn_sinf(r3 + 0.25f);

    float p0 = fa * c2, p1 = fa * s2;
    fp16x2 lo = __builtin_amdgcn_cvt_pkrtz(p0 * c3, p0 * s3);
    fp16x2 hi = __builtin_amdgcn_cvt_pkrtz(p1 * c3, p1 * s3);
    half4 bST;
    bST[0] = (_Float16)lo[0]; bST[1] = (_Float16)lo[1];
    bST[2] = (_Float16)hi[0]; bST[3] = (_Float16)hi[1];

    const f32x4 zero4 = {0.f, 0.f, 0.f, 0.f};
    f32x4 y = __builtin_amdgcn_mfma_f32_16x16x16f16(aU, bST, zero4, 0, 0, 0);

    fp16x2 plo = __builtin_amdgcn_cvt_pkrtz(y[0] * y[0], y[1] * y[1]);
    fp16x2 phi = __builtin_amdgcn_cvt_pkrtz(y[2] * y[2], y[3] * y[3]);
    half4 bP;
    bP[0] = (_Float16)plo[0]; bP[1] = (_Float16)plo[1];
    bP[2] = (_Float16)phi[0]; bP[3] = (_Float16)phi[1];

    f32x4 m = __builtin_amdgcn_mfma_f32_16x16x16f16(aS, bP, zero4, 0, 0, 0);

    if (g == 0 && patch < total) {
        float4 res = make_float4(m[0], m[1], m[2], m[3]);
        *reinterpret_cast<float4*>(out + (size_t)patch * 4) = res;
    }
}

__global__ __launch_bounds__(256) void quanv_mfma(
    const float* __restrict__ x,
    const float* __restrict__ U,
    float* __restrict__ out,
    int total, int ipw, int rem)
{
    const int lane = threadIdx.x & 63;
    const int wave = (blockIdx.x * blockDim.x + threadIdx.x) >> 6;
    const int p16  = lane & 15;
    const int g    = lane >> 4;

    // A1 = U fragment: U[p16][4g+i]
    half4 aU;
    {
        const float* up = U + p16 * 16 + 4 * g;
        aU[0] = (_Float16)up[0];
        aU[1] = (_Float16)up[1];
        aU[2] = (_Float16)up[2];
        aU[3] = (_Float16)up[3];
    }
    // A2 = tiled PauliZ signs: Ztile[p16][e=4g+i], wire = p16&3 (exact in f16)
    half4 aS;
    {
        int w = p16 & 3;
        #pragma unroll
        for (int i = 0; i < 4; ++i) {
            int e = 4 * g + i;
            aS[i] = ((e >> (3 - w)) & 1) ? (_Float16)-1.f : (_Float16)1.f;
        }
    }
    // fa = sel(g&2: s0,c0) * sel(g&1: s1,c1): +0.25 rev turns sin into cos
    const float q0 = (g & 2) ? 0.f : 0.25f;
    const float q1 = (g & 1) ? 0.f : 0.25f;

    int cnt = ipw + (wave < rem ? 1 : 0);
    if (cnt <= 0) return;
    const int it0 = wave * ipw + (wave < rem ? wave : rem);
    const int na = (cnt + 1) >> 1;   // stream A batches (even slots)
    const int nb = cnt >> 1;         // stream B batches (odd slots)

    // stream A state + first load
    int pA = it0 * 16 + p16;
    int bimg = pA / 196;
    int ppA = pA - bimg * 196;
    int boA = bimg * 784;
    float2 topA, botA;
    ldpix(x, elem_of(ppA, boA), topA, botA);

    // stream B state + first load
    int pB = pA + 16, ppB = 0, boB = 0;
    float2 topB, botB;
    if (nb > 0) {
        ppB = ppA + 16; boB = boA;
        if (ppB >= 196) { ppB -= 196; boB += 784; }
        ldpix(x, elem_of(ppB, boB), topB, botB);
    }

    for (int t = 0; t < nb; ++t) {
        // prefetch A_{t+1}, then compute A_t
        int curP = pA; float2 cT = topA, cB = botA;
        if (t + 1 < na) {
            pA += 32; ppA += 32;
            if (ppA >= 196) { ppA -= 196; boA += 784; }
            ldpix(x, elem_of(ppA, boA), topA, botA);
        }
        compute_batch(cT, cB, q0, q1, aU, aS, curP, g, out, total);

        // prefetch B_{t+1}, then compute B_t
        curP = pB; cT = topB; cB = botB;
        if (t + 1 < nb) {
            pB += 32; ppB += 32;
            if (ppB >= 196) { ppB -= 196; boB += 784; }
            ldpix(x, elem_of(ppB, boB), topB, botB);
        }
        compute_batch(cT, cB, q0, q1, aU, aS, curP, g, out, total);
    }
    if (na > nb)  // odd cnt: one leftover A batch, already loaded
        compute_batch(topA, botA, q0, q1, aU, aS, pA, g, out, total);
}

extern "C" void kernel_launch(void* const* d_in, const int* in_sizes, int n_in,
                              void* d_out, int out_size, void* d_ws, size_t ws_size,
                              hipStream_t stream) {
    const float* x = (const float*)d_in[0];
    const float* U = (const float*)d_in[1];
    float* out = (float*)d_out;

    int B = in_sizes[0] / 784;
    int total = B * 196;                  // 6,422,528 patches
    int nit = (total + 15) / 16;          // 401,408 16-patch batches

    int nblocks = 2048;
    int nwaves = nblocks * (256 / 64);    // 8192 waves -> 49 batches/wave, rem 0
    int ipw = nit / nwaves;
    int rem = nit % nwaves;

    quanv_mfma<<<nblocks, 256, 0, stream>>>(x, U, out, total, ipw, rem);
}

// Round 5
// 38.863 us; speedup vs baseline: 1.6769x; 1.3596x over previous
//
#include <hip/hip_runtime.h>

typedef _Float16 half4 __attribute__((ext_vector_type(4)));
typedef _Float16 h2 __attribute__((ext_vector_type(2)));
typedef __fp16 fp16x2 __attribute__((ext_vector_type(2)));
typedef float f32x4 __attribute__((ext_vector_type(4)));

#define SINCONST 0.07957747154594767f  // 0.5 rad in revolutions

// Per wave macro-iter: 64 patches.
//  Phase1: lane l owns patch (pbase+l): 2 float2 loads, 8 sin/cos,
//          a=(c0c1,c0s1,s0c1,s0s1), q=(c2c3,c2s3,s2c3,s2s3) -> f16 -> LDS.
//          LDS per wave-buffer: adup[64][4] u32 (a_g dup-packed) @+0,
//          qv[64] u32x2 @+1024.  (2-way-or-less bank aliasing on reads)
//  Phase2: 4 sub-batches t: lane (g,p16), patch pt=t*16+p16:
//          bST[i]=a_g*q_i via 2 v_pk_mul_f16; MFMA1 Y=U*ST^T; square in f16;
//          MFMA2 M=Ztile*Y^2; lanes g==0 store float4 (coalesced).
__global__ __launch_bounds__(256) void quanv(
    const float* __restrict__ x,
    const float* __restrict__ U,
    float* __restrict__ out,
    int total, int ipw, int rem)
{
    __shared__ __align__(16) unsigned int smem[4 * 2 * 1536 / 4];

    const int tid  = threadIdx.x;
    const int lane = tid & 63;
    const int wib  = tid >> 6;
    const int wave = (blockIdx.x * 256 + tid) >> 6;
    const int p16  = lane & 15;
    const int g    = lane >> 4;

    unsigned int* wsmem = smem + wib * (2 * 1536 / 4);

    // A1 = U fragment: U[p16][4g+i]  (validated layout)
    half4 aU;
    {
        const float* up = U + p16 * 16 + 4 * g;
        aU[0] = (_Float16)up[0];
        aU[1] = (_Float16)up[1];
        aU[2] = (_Float16)up[2];
        aU[3] = (_Float16)up[3];
    }
    // A2 = tiled PauliZ signs: Ztile[p16][e=4g+i], wire=p16&3 (exact in f16)
    half4 aS;
    {
        int w = p16 & 3;
        #pragma unroll
        for (int i = 0; i < 4; ++i) {
            int e = 4 * g + i;
            aS[i] = ((e >> (3 - w)) & 1) ? (_Float16)-1.f : (_Float16)1.f;
        }
    }

    int cnt = ipw + (wave < rem ? 1 : 0);
    if (cnt <= 0) return;
    const int mac0 = wave * ipw + (wave < rem ? wave : rem);

    // per-lane patch bookkeeping (lane owns patch P = (mac0+j)*64 + lane)
    int P0 = mac0 * 64 + lane;
    int pc = P0 < total ? P0 : total - 1;
    int img = pc / 196;
    int pp  = pc - img * 196;          // patch-in-image, [0,195]
    int bo  = img * 784;               // image base offset (floats)

    float2 curT, curB, nxtT, nxtB;
    {
        int r = (pp * 2341) >> 15;     // pp/14, exact for pp<=195
        const float2* ptr = reinterpret_cast<const float2*>(x + bo + 2 * pp + 28 * r);
        curT = ptr[0];
        curB = ptr[14];
    }

    for (int j = 0; j < cnt; ++j) {
        const int pbase = (mac0 + j) * 64;

        // prefetch next macro-iter's pixels (wave-uniform branch)
        if (j + 1 < cnt) {
            pp += 64;
            if (pp >= 196) { pp -= 196; bo += 784; }
            int r = (pp * 2341) >> 15;
            const float2* ptr = reinterpret_cast<const float2*>(x + bo + 2 * pp + 28 * r);
            nxtT = ptr[0];
            nxtB = ptr[14];
        }

        // ---- phase 1: own-patch state factors -> LDS ----
        float r0 = curT.x * SINCONST, r1 = curT.y * SINCONST;
        float r2 = curB.x * SINCONST, r3 = curB.y * SINCONST;
        float s0 = __builtin_amdgcn_sinf(r0), c0 = __builtin_amdgcn_cosf(r0);
        float s1 = __builtin_amdgcn_sinf(r1), c1 = __builtin_amdgcn_cosf(r1);
        float s2 = __builtin_amdgcn_sinf(r2), c2 = __builtin_amdgcn_cosf(r2);
        float s3 = __builtin_amdgcn_sinf(r3), c3 = __builtin_amdgcn_cosf(r3);

        float a0 = c0 * c1, a1 = c0 * s1, a2 = s0 * c1, a3 = s0 * s1;
        float q0 = c2 * c3, q1 = c2 * s3, q2 = s2 * c3, q3 = s2 * s3;

        uint4 ad;
        ad.x = __builtin_bit_cast(unsigned int, __builtin_amdgcn_cvt_pkrtz(a0, a0));
        ad.y = __builtin_bit_cast(unsigned int, __builtin_amdgcn_cvt_pkrtz(a1, a1));
        ad.z = __builtin_bit_cast(unsigned int, __builtin_amdgcn_cvt_pkrtz(a2, a2));
        ad.w = __builtin_bit_cast(unsigned int, __builtin_amdgcn_cvt_pkrtz(a3, a3));
        uint2 qd;
        qd.x = __builtin_bit_cast(unsigned int, __builtin_amdgcn_cvt_pkrtz(q0, q1));
        qd.y = __builtin_bit_cast(unsigned int, __builtin_amdgcn_cvt_pkrtz(q2, q3));

        unsigned int* buf = wsmem + (j & 1) * (1536 / 4);
        *reinterpret_cast<uint4*>(buf + lane * 4) = ad;          // ds_write_b128
        *reinterpret_cast<uint2*>(buf + 256 + lane * 2) = qd;    // ds_write_b64

        // ---- phase 2: 4 MFMA sub-batches ----
        const unsigned int* adArr = buf;          // adup[pt][g] at dword pt*4+g
        const uint2* qArr = reinterpret_cast<const uint2*>(buf + 256);

        #pragma unroll
        for (int t = 0; t < 4; ++t) {
            const int pt = t * 16 + p16;
            unsigned int adw = adArr[pt * 4 + g];  // imm offset t*256B
            uint2 qw = qArr[pt];                   // imm offset 1024+t*128B

            h2 ag  = __builtin_bit_cast(h2, adw);
            h2 q01 = __builtin_bit_cast(h2, qw.x);
            h2 q23 = __builtin_bit_cast(h2, qw.y);
            h2 blo = ag * q01;                     // v_pk_mul_f16
            h2 bhi = ag * q23;
            half4 bST = __builtin_shufflevector(blo, bhi, 0, 1, 2, 3);

            const f32x4 zero4 = {0.f, 0.f, 0.f, 0.f};
            f32x4 y = __builtin_amdgcn_mfma_f32_16x16x16f16(aU, bST, zero4, 0, 0, 0);

            h2 y01 = __builtin_bit_cast(h2, __builtin_amdgcn_cvt_pkrtz(y[0], y[1]));
            h2 y23 = __builtin_bit_cast(h2, __builtin_amdgcn_cvt_pkrtz(y[2], y[3]));
            h2 p01 = y01 * y01;                    // squares in packed f16
            h2 p23 = y23 * y23;
            half4 bP = __builtin_shufflevector(p01, p23, 0, 1, 2, 3);

            f32x4 m = __builtin_amdgcn_mfma_f32_16x16x16f16(aS, bP, zero4, 0, 0, 0);

            int Ps = pbase + pt;
            if (g == 0 && Ps < total) {
                float4 res = make_float4(m[0], m[1], m[2], m[3]);
                *reinterpret_cast<float4*>(out + (size_t)Ps * 4) = res;
            }
        }

        if (j + 1 < cnt) { curT = nxtT; curB = nxtB; }
    }
}

extern "C" void kernel_launch(void* const* d_in, const int* in_sizes, int n_in,
                              void* d_out, int out_size, void* d_ws, size_t ws_size,
                              hipStream_t stream) {
    const float* x = (const float*)d_in[0];
    const float* U = (const float*)d_in[1];
    float* out = (float*)d_out;

    int B = in_sizes[0] / 784;
    int total = B * 196;                  // 6,422,528 patches
    int nmac = (total + 63) / 64;         // 100,352 macro-iters (64 patches each)

    int nblocks = 2048;
    int nwaves = nblocks * (256 / 64);    // 8192 waves
    int ipw = nmac / nwaves;              // 12
    int rem = nmac % nwaves;              // 2048

    quanv<<<nblocks, 256, 0, stream>>>(x, U, out, total, ipw, rem);
}